// Round 1
// baseline (1031.306 us; speedup 1.0000x reference)
//
#include <hip/hip_runtime.h>
#include <hip/hip_bf16.h>

typedef __bf16 bf16x8 __attribute__((ext_vector_type(8)));
typedef float  f32x4  __attribute__((ext_vector_type(4)));

#define MFMA16 __builtin_amdgcn_mfma_f32_16x16x32_bf16

// ---------------------------------------------------------------------------
// Weight prep: fp32 [K][Nw] row-major -> bf16 B-fragment layout
// [kchunk][ntile][lane][8], where lane = (k_quad<<4) | n_low4,
// frag[j] = W[kchunk*32 + quad*8 + j][ntile*16 + (lane&15)].
// One 16B coalesced load per (kchunk, ntile, lane) at GEMM time.
// ---------------------------------------------------------------------------
__global__ void shuffle_weights(const float* __restrict__ W, __bf16* __restrict__ out,
                                int K, int Nw) {
    int tid = blockIdx.x * 256 + threadIdx.x;
    int NT = Nw >> 4;
    int total = (K >> 5) * NT * 64;
    if (tid >= total) return;
    int lane = tid & 63;
    int rest = tid >> 6;
    int nt = rest % NT;
    int kc = rest / NT;
    int q = lane >> 4;
    int n = nt * 16 + (lane & 15);
    const float* src = W + (size_t)(kc * 32 + q * 8) * Nw + n;
    __bf16* dst = out + (size_t)tid * 8;
#pragma unroll
    for (int j = 0; j < 8; ++j) dst[j] = (__bf16)src[(size_t)j * Nw];
}

// ---------------------------------------------------------------------------
// Phase 1: h = relu(relu(X@W1 + b1)@W2 + b2), store bf16 [N][128].
// Block = 256 threads = 4 waves; block covers 128 rows, wave covers 32 rows
// (2 M-tiles of 16). A-frags of X loaded straight from global (fp32->bf16);
// h1 goes through LDS (same-wave transpose C-layout -> A-layout).
// ---------------------------------------------------------------------------
__global__ __launch_bounds__(256) void phase1(
    const float* __restrict__ feat,
    const __bf16* __restrict__ W1s, const float* __restrict__ b1,
    const __bf16* __restrict__ W2s, const float* __restrict__ b2,
    __bf16* __restrict__ hbuf)
{
    __shared__ __bf16 h1s[128 * 136];  // row stride 136 bf16 = 272B (16B-aligned, non-pow2)
    const int lane = threadIdx.x & 63;
    const int wave = threadIdx.x >> 6;
    const int q    = lane >> 4;
    const int mr   = lane & 15;
    const long base = (long)blockIdx.x * 128 + wave * 32;

    const f32x4 fz = {0.f, 0.f, 0.f, 0.f};

    // ---- layer 1: [32 x 256] @ [256 x 128] ----
    f32x4 acc[2][8];
#pragma unroll
    for (int mt = 0; mt < 2; ++mt)
#pragma unroll
        for (int nt = 0; nt < 8; ++nt) acc[mt][nt] = fz;

#pragma unroll
    for (int kc = 0; kc < 8; ++kc) {
        bf16x8 af[2];
#pragma unroll
        for (int mt = 0; mt < 2; ++mt) {
            const float* p = feat + (base + mt * 16 + mr) * 256 + kc * 32 + q * 8;
            f32x4 f0 = *(const f32x4*)p;
            f32x4 f1 = *(const f32x4*)(p + 4);
#pragma unroll
            for (int j = 0; j < 4; ++j) {
                af[mt][j]     = (__bf16)f0[j];
                af[mt][4 + j] = (__bf16)f1[j];
            }
        }
#pragma unroll
        for (int nt = 0; nt < 8; ++nt) {
            bf16x8 bf = *(const bf16x8*)(W1s + (size_t)((kc * 8 + nt) * 64 + lane) * 8);
            acc[0][nt] = MFMA16(af[0], bf, acc[0][nt], 0, 0, 0);
            acc[1][nt] = MFMA16(af[1], bf, acc[1][nt], 0, 0, 0);
        }
    }

    // bias + relu -> LDS (C-layout: col = mr-ish = lane&15, row = q*4+r)
#pragma unroll
    for (int mt = 0; mt < 2; ++mt)
#pragma unroll
        for (int nt = 0; nt < 8; ++nt) {
            int c = nt * 16 + mr;
            float bb = b1[c];
#pragma unroll
            for (int r = 0; r < 4; ++r) {
                float v = acc[mt][nt][r] + bb;
                v = v > 0.f ? v : 0.f;
                h1s[(wave * 32 + mt * 16 + q * 4 + r) * 136 + c] = (__bf16)v;
            }
        }
    __syncthreads();

    // ---- layer 2: [32 x 128] @ [128 x 128] ----
    bf16x8 af2[2][4];
#pragma unroll
    for (int mt = 0; mt < 2; ++mt)
#pragma unroll
        for (int kc = 0; kc < 4; ++kc)
            af2[mt][kc] = *(const bf16x8*)&h1s[(wave * 32 + mt * 16 + mr) * 136 + kc * 32 + q * 8];

    f32x4 acc2[2][8];
#pragma unroll
    for (int mt = 0; mt < 2; ++mt)
#pragma unroll
        for (int nt = 0; nt < 8; ++nt) acc2[mt][nt] = fz;

#pragma unroll
    for (int kc = 0; kc < 4; ++kc)
#pragma unroll
        for (int nt = 0; nt < 8; ++nt) {
            bf16x8 bf = *(const bf16x8*)(W2s + (size_t)((kc * 8 + nt) * 64 + lane) * 8);
            acc2[0][nt] = MFMA16(af2[0][kc], bf, acc2[0][nt], 0, 0, 0);
            acc2[1][nt] = MFMA16(af2[1][kc], bf, acc2[1][nt], 0, 0, 0);
        }

    // bias + relu -> hbuf bf16 [N][128]
#pragma unroll
    for (int mt = 0; mt < 2; ++mt)
#pragma unroll
        for (int nt = 0; nt < 8; ++nt) {
            int c = nt * 16 + mr;
            float bb = b2[c];
#pragma unroll
            for (int r = 0; r < 4; ++r) {
                float v = acc2[mt][nt][r] + bb;
                v = v > 0.f ? v : 0.f;
                hbuf[(base + mt * 16 + q * 4 + r) * 128 + c] = (__bf16)v;
            }
        }
}

// ---------------------------------------------------------------------------
// Phase 2: edge = [h[parent] | h] @ We + be  (K=256, Nw=256),
//          unary = h @ Wu + bu               (K=128, Nw=16).
// No LDS, no barriers. A-frags gathered from hbuf, held in regs across
// both N-halves of We. Out row = [unary(16) | edge(256)] fp32, stride 272.
// ---------------------------------------------------------------------------
__global__ __launch_bounds__(256) void phase2(
    const __bf16* __restrict__ hbuf, const int* __restrict__ parent,
    const __bf16* __restrict__ WeS, const float* __restrict__ be,
    const __bf16* __restrict__ WuS, const float* __restrict__ bu,
    float* __restrict__ out)
{
    const int lane = threadIdx.x & 63;
    const int q    = lane >> 4;
    const int mr   = lane & 15;
    const long base = (long)blockIdx.x * 128 + (threadIdx.x >> 6) * 32;

    const f32x4 fz = {0.f, 0.f, 0.f, 0.f};

    // A-frags: kc 0..3 -> h[parent], kc 4..7 -> h[node]
    bf16x8 af[2][8];
#pragma unroll
    for (int mt = 0; mt < 2; ++mt) {
        long node = base + mt * 16 + mr;
        long par  = parent[node];
        const __bf16* hp = hbuf + par * 128;
        const __bf16* hn = hbuf + node * 128;
#pragma unroll
        for (int kc = 0; kc < 4; ++kc) {
            af[mt][kc]     = *(const bf16x8*)(hp + kc * 32 + q * 8);
            af[mt][kc + 4] = *(const bf16x8*)(hn + kc * 32 + q * 8);
        }
    }

    // ---- unary: h @ Wu (K=128 => child half, kc 4..7) ----
    f32x4 accu[2];
    accu[0] = fz; accu[1] = fz;
#pragma unroll
    for (int kc = 0; kc < 4; ++kc) {
        bf16x8 bf = *(const bf16x8*)(WuS + (size_t)(kc * 64 + lane) * 8);
        accu[0] = MFMA16(af[0][kc + 4], bf, accu[0], 0, 0, 0);
        accu[1] = MFMA16(af[1][kc + 4], bf, accu[1], 0, 0, 0);
    }
    {
        float bb = bu[mr];
#pragma unroll
        for (int mt = 0; mt < 2; ++mt)
#pragma unroll
            for (int r = 0; r < 4; ++r)
                out[(base + mt * 16 + q * 4 + r) * 272 + mr] = accu[mt][r] + bb;
    }

    // ---- edge: two N-halves of 128 cols each ----
#pragma unroll 1
    for (int nh = 0; nh < 2; ++nh) {
        f32x4 acc[2][8];
#pragma unroll
        for (int mt = 0; mt < 2; ++mt)
#pragma unroll
            for (int nt = 0; nt < 8; ++nt) acc[mt][nt] = fz;

#pragma unroll
        for (int kc = 0; kc < 8; ++kc)
#pragma unroll
            for (int nt = 0; nt < 8; ++nt) {
                bf16x8 bf = *(const bf16x8*)(WeS + (size_t)((kc * 16 + nh * 8 + nt) * 64 + lane) * 8);
                acc[0][nt] = MFMA16(af[0][kc], bf, acc[0][nt], 0, 0, 0);
                acc[1][nt] = MFMA16(af[1][kc], bf, acc[1][nt], 0, 0, 0);
            }

#pragma unroll
        for (int mt = 0; mt < 2; ++mt)
#pragma unroll
            for (int nt = 0; nt < 8; ++nt) {
                int c = nh * 128 + nt * 16 + mr;
                float bb = be[c];
#pragma unroll
                for (int r = 0; r < 4; ++r)
                    out[(base + mt * 16 + q * 4 + r) * 272 + 16 + c] = acc[mt][nt][r] + bb;
            }
    }
}

// ---------------------------------------------------------------------------
// ws layout (bytes):
//   0        W1s   (256x128 bf16 shuffled)  65536
//   65536    W2s   (128x128)                32768
//   98304    WuS   (128x16)                  4096
//   102400   WeS   (256x256)               131072
//   233472   hbuf  (400000x128 bf16)   102400000
// total ~97.9 MB
// ---------------------------------------------------------------------------
extern "C" void kernel_launch(void* const* d_in, const int* in_sizes, int n_in,
                              void* d_out, int out_size, void* d_ws, size_t ws_size,
                              hipStream_t stream) {
    const float* feat  = (const float*)d_in[0];
    const int*   parent = (const int*)d_in[1];
    const float* W1 = (const float*)d_in[2];
    const float* b1 = (const float*)d_in[3];
    const float* W2 = (const float*)d_in[4];
    const float* b2 = (const float*)d_in[5];
    const float* Wu = (const float*)d_in[6];
    const float* bu = (const float*)d_in[7];
    const float* We = (const float*)d_in[8];
    const float* be = (const float*)d_in[9];
    float* out = (float*)d_out;

    char* ws = (char*)d_ws;
    __bf16* W1s  = (__bf16*)(ws);
    __bf16* W2s  = (__bf16*)(ws + 65536);
    __bf16* WuS  = (__bf16*)(ws + 98304);
    __bf16* WeS  = (__bf16*)(ws + 102400);
    __bf16* hbuf = (__bf16*)(ws + 233472);

    shuffle_weights<<<16, 256, 0, stream>>>(W1, W1s, 256, 128);
    shuffle_weights<<<8,  256, 0, stream>>>(W2, W2s, 128, 128);
    shuffle_weights<<<1,  256, 0, stream>>>(Wu, WuS, 128, 16);
    shuffle_weights<<<32, 256, 0, stream>>>(We, WeS, 256, 256);

    const int nblocks = 400000 / 128;  // 3125
    phase1<<<nblocks, 256, 0, stream>>>(feat, W1s, b1, W2s, b2, hbuf);
    phase2<<<nblocks, 256, 0, stream>>>(hbuf, parent, WeS, be, WuS, bu, out);
}